// Round 6
// baseline (391.844 us; speedup 1.0000x reference)
//
#include <hip/hip_runtime.h>
#include <hip/hip_bf16.h>
#include <math.h>

typedef __bf16 bf16;
typedef __bf16 bf16x8 __attribute__((ext_vector_type(8)));
typedef float f32x4 __attribute__((ext_vector_type(4)));

#define S_LEN 2048
#define HID_D 4096
#define NH 32
#define NKV 8
#define HD 128
// D^-0.5 * log2(e): softmax computed in exp2 domain
#define SCALE_LOG2 (0.08838834764831843f * 1.4426950408889634f)

__device__ __forceinline__ void gload_lds16(const void* g, void* lds) {
  __builtin_amdgcn_global_load_lds((__attribute__((address_space(1))) void*)g,
                                   (__attribute__((address_space(3))) void*)lds, 16, 0, 0);
}

#define MEMFENCE asm volatile("" ::: "memory")

// ---------------- f32 -> bf16 convert (vectorized, grid-stride) ----------------
__global__ __launch_bounds__(256) void cvt_kernel(const float* __restrict__ in,
                                                  bf16* __restrict__ out, int n8) {
  int i = blockIdx.x * blockDim.x + threadIdx.x;
  int stride = gridDim.x * blockDim.x;
  for (; i < n8; i += stride) {
    const float4* p = (const float4*)in + 2 * (size_t)i;
    float4 a = p[0], b = p[1];
    bf16x8 o;
    o[0] = (bf16)a.x; o[1] = (bf16)a.y; o[2] = (bf16)a.z; o[3] = (bf16)a.w;
    o[4] = (bf16)b.x; o[5] = (bf16)b.y; o[6] = (bf16)b.z; o[7] = (bf16)b.w;
    *((bf16x8*)out + i) = o;
  }
}

// ---------------- f32 add (split-K reduce): out += part -----------------------
__global__ __launch_bounds__(256) void add_kernel(float* __restrict__ out,
                                                  const float* __restrict__ part, int n4) {
  int i = blockIdx.x * blockDim.x + threadIdx.x;
  int stride = gridDim.x * blockDim.x;
  for (; i < n4; i += stride) {
    float4 a = ((const float4*)out)[i];
    float4 b = ((const float4*)part)[i];
    a.x += b.x; a.y += b.y; a.z += b.z; a.w += b.w;
    ((float4*)out)[i] = a;
  }
}

// ---------------- 256x256 quadrant-scheduled 8-phase bf16 NT GEMM --------------
// C[M][N] = A[M][Ks]*B[N][Ks]^T over K-slice. 512 thr = 8 waves (2M x 4N),
// wave C-tile = rows {q*128+wr*64..+63} x cols {r*128+wc*32..+31} per (q,r).
// LDS 128KB: [dbuf2][op2][half2][16KB]; half = 128 rows x 64 k x bf16.
// Per K-tile 4 phases of 16 MFMA: p1{dsA.h0+dsB.h0}, p2{dsB.h1}, p3{dsA.h1,
// B.h0 regs retained}, p4{no ds}. Stages: p1->(t+1).A.h1, p2->(t+2).A.h0,
// p3->(t+2).B.h0, p4->(t+2).B.h1 (each slot retired one phase earlier).
// vmcnt(6) once per tile at p4 => all of (t+1)'s halves resident at t+1.p1.
// Swizzle: chunk c at row rw stored/read at c ^ (rw&7) (128B pitch, 2-way=free).
__global__ __launch_bounds__(512, 2) void gemm256(const bf16* __restrict__ A,
                                                  const bf16* __restrict__ B,
                                                  float* __restrict__ C0,
                                                  float* __restrict__ C1,
                                                  int N, int Kfull, int Kslice, int T) {
  __shared__ __align__(16) char lds[131072];
  const int t = threadIdx.x, l = t & 63, w = t >> 6;
  const int wr = w >> 2, wc = w & 3;
  const int l15 = l & 15, lg = l >> 4;
  const int s7 = l15 & 7;

  const int nwg = gridDim.x * gridDim.y;
  const int lin = blockIdx.y * gridDim.x + blockIdx.x;
  const int swz = (lin & 7) * (nwg >> 3) + (lin >> 3);
  const int n0 = (swz % gridDim.x) * 256;
  const int m0 = (swz / gridDim.x) * 256;
  const size_t kbase = (size_t)blockIdx.z * Kslice;
  float* __restrict__ C = blockIdx.z ? C1 : C0;

  auto stage = [&](int d, int op, int hf, int tau) {
    char* dst = lds + d * 65536 + op * 32768 + hf * 16384;
    const bf16* src = op ? B : A;
    const int rbase = (op ? n0 : m0) + hf * 128;
    const size_t kpos = kbase + (size_t)tau * 64;
#pragma unroll
    for (int i = 0; i < 2; i++) {
      int q = i * 512 + t;
      int r = q >> 3;                 // 8 16B-chunks per 128B row
      int c = (q & 7) ^ (r & 7);      // inverse-swizzled source chunk
      gload_lds16(src + (size_t)(rbase + r) * Kfull + kpos + c * 8, dst + q * 16);
    }
  };

  f32x4 acc[2][2][4][2] = {};
  bf16x8 a[4][2], b0[2][2], b1[2][2];

  auto ldsA = [&](int d, int hf) {
    const char* base = lds + d * 65536 + hf * 16384;
#pragma unroll
    for (int mf = 0; mf < 4; mf++) {
      int row = wr * 64 + mf * 16 + l15;
#pragma unroll
      for (int ks = 0; ks < 2; ks++)
        a[mf][ks] = *(const bf16x8*)(base + row * 128 + (((ks * 4 + lg) ^ s7) << 4));
    }
  };
  auto ldsB = [&](int d, int hf, bf16x8 bb[2][2]) {
    const char* base = lds + d * 65536 + 32768 + hf * 16384;
#pragma unroll
    for (int nf = 0; nf < 2; nf++) {
      int row = wc * 32 + nf * 16 + l15;
#pragma unroll
      for (int ks = 0; ks < 2; ks++)
        bb[nf][ks] = *(const bf16x8*)(base + row * 128 + (((ks * 4 + lg) ^ s7) << 4));
    }
  };

#define LEAD_BAR                                           \
  MEMFENCE; __builtin_amdgcn_s_barrier(); MEMFENCE;        \
  asm volatile("s_waitcnt lgkmcnt(0)" ::: "memory");       \
  __builtin_amdgcn_sched_barrier(0);
#define TRAIL_BAR MEMFENCE; __builtin_amdgcn_s_barrier(); MEMFENCE;

#define MMAQ(q, r, bb)                                                          \
  __builtin_amdgcn_s_setprio(1);                                               \
  _Pragma("unroll") for (int mf = 0; mf < 4; mf++)                              \
  _Pragma("unroll") for (int nf = 0; nf < 2; nf++)                              \
  _Pragma("unroll") for (int ks = 0; ks < 2; ks++)                              \
      acc[q][r][mf][nf] = __builtin_amdgcn_mfma_f32_16x16x32_bf16(              \
          a[mf][ks], bb[nf][ks], acc[q][r][mf][nf], 0, 0, 0);                   \
  __builtin_amdgcn_s_setprio(0);

  // prologue: tile0 all 4 halves, tile1 first 3 halves (A.h1 staged in loop p1)
  stage(0, 0, 0, 0); stage(0, 1, 0, 0); stage(0, 1, 1, 0); stage(0, 0, 1, 0);
  stage(1, 0, 0, 1); stage(1, 1, 0, 1); stage(1, 1, 1, 1);
  asm volatile("s_waitcnt vmcnt(6)" ::: "memory");  // tile0 resident
  TRAIL_BAR;

  for (int tau = 0; tau < T; tau++) {
    const int d = tau & 1, dn = d ^ 1;
    const bool s1 = tau + 1 < T, s2 = tau + 2 < T;
    // p1: consume (d,A.h0)+(d,B.h0); stage (t+1).A.h1
    if (s1) stage(dn, 0, 1, tau + 1);
    ldsA(d, 0); ldsB(d, 0, b0);
    LEAD_BAR; MMAQ(0, 0, b0); TRAIL_BAR;
    // p2: consume (d,B.h1); stage (t+2).A.h0 (slot retired after p1)
    if (s2) stage(d, 0, 0, tau + 2);
    ldsB(d, 1, b1);
    LEAD_BAR; MMAQ(0, 1, b1); TRAIL_BAR;
    // p3: consume (d,A.h1); B.h0 retained in regs; stage (t+2).B.h0
    if (s2) stage(d, 1, 0, tau + 2);
    ldsA(d, 1);
    LEAD_BAR; MMAQ(1, 0, b0); TRAIL_BAR;
    // p4: pure MFMA; stage (t+2).B.h1; counted vmcnt once per tile
    if (s2) stage(d, 1, 1, tau + 2);
    if (s2) { asm volatile("s_waitcnt vmcnt(6)" ::: "memory"); }
    else    { asm volatile("s_waitcnt vmcnt(0)" ::: "memory"); }
    MEMFENCE; __builtin_amdgcn_s_barrier(); MEMFENCE;
    MMAQ(1, 1, b1); TRAIL_BAR;
  }

  // epilogue
#pragma unroll
  for (int q = 0; q < 2; q++)
#pragma unroll
    for (int r = 0; r < 2; r++)
#pragma unroll
      for (int mf = 0; mf < 4; mf++) {
        int row = m0 + q * 128 + wr * 64 + mf * 16 + lg * 4;
#pragma unroll
        for (int nf = 0; nf < 2; nf++) {
          int col = n0 + r * 128 + wc * 32 + nf * 16 + l15;
          float* Cp = C + (size_t)row * N + col;
#pragma unroll
          for (int rr = 0; rr < 4; rr++) Cp[(size_t)rr * N] = acc[q][r][mf][nf][rr];
        }
      }
}

// ---------------- fused RMSNorm + RoPE + layout kernel -------------------------
__global__ __launch_bounds__(256) void prep_kernel(const float* __restrict__ QKV,
                                                   const float* __restrict__ qw,
                                                   const float* __restrict__ kw,
                                                   const int* __restrict__ pos_ids,
                                                   bf16* __restrict__ Qb,
                                                   bf16* __restrict__ Kb,
                                                   bf16* __restrict__ Vt) {
  __shared__ __align__(16) float row[6144];
  __shared__ float cs[64];
  __shared__ float red[8];
  const int s = blockIdx.x, t = threadIdx.x;

  const float4* src = (const float4*)(QKV + (size_t)s * 6144);
#pragma unroll
  for (int i = 0; i < 6; i++) ((float4*)row)[t + i * 256] = src[t + i * 256];

  if (t < 32) {
    float p = (float)pos_ids[s];
    float ang = p * powf(10000.0f, -(float)t * (1.0f / 32.0f));
    float sn, cn;
    sincosf(ang, &sn, &cn);
    cs[t] = cn;
    cs[32 + t] = sn;
  }
  __syncthreads();

  float aq = 0.f, ak = 0.f;
  for (int i = t; i < 4096; i += 256) { float v = row[i]; aq += v * v; }
  for (int i = 4096 + t; i < 5120; i += 256) { float v = row[i]; ak += v * v; }
#pragma unroll
  for (int off = 32; off; off >>= 1) {
    aq += __shfl_down(aq, off);
    ak += __shfl_down(ak, off);
  }
  if ((t & 63) == 0) { red[t >> 6] = aq; red[4 + (t >> 6)] = ak; }
  __syncthreads();
  const float scq = rsqrtf((red[0] + red[1] + red[2] + red[3]) * (1.0f / 4096.0f) + 1e-6f);
  const float sck = rsqrtf((red[4] + red[5] + red[6] + red[7]) * (1.0f / 1024.0f) + 1e-6f);

  for (int e = t; e < 4096; e += 256) {
    int d = e & 127;
    int hh = e >> 7;
    float val = row[e] * scq * qw[e];
    float o;
    if (d < 32)       o = val * cs[d] - (row[e + 32] * scq * qw[e + 32]) * cs[32 + d];
    else if (d < 64)  o = val * cs[d - 32] + (row[e - 32] * scq * qw[e - 32]) * cs[d];
    else              o = val;
    Qb[((size_t)hh * S_LEN + s) * HD + d] = (bf16)o;
  }
  for (int e = t; e < 1024; e += 256) {
    int d = e & 127;
    int hh = e >> 7;
    int ri = 4096 + e;
    float val = row[ri] * sck * kw[e];
    float o;
    if (d < 32)       o = val * cs[d] - (row[ri + 32] * sck * kw[e + 32]) * cs[32 + d];
    else if (d < 64)  o = val * cs[d - 32] + (row[ri - 32] * sck * kw[e - 32]) * cs[d];
    else              o = val;
    Kb[((size_t)hh * S_LEN + s) * HD + d] = (bf16)o;
  }
  for (int e = t; e < 1024; e += 256) {
    int d = e & 127;
    int hh = e >> 7;
    Vt[((size_t)hh * HD + d) * S_LEN + s] = (bf16)row[5120 + e];
  }
}

// ---------------- flash attention (GQA, causal, LDS-pipelined, folded) ---------
__global__ __launch_bounds__(256, 2) void attn_kernel(const bf16* __restrict__ Qb,
                                                      const bf16* __restrict__ Kb,
                                                      const bf16* __restrict__ Vt,
                                                      bf16* __restrict__ Ctx) {
  __shared__ __align__(16) char KB[2][16384];  // 2 x 64 rows x 256B
  __shared__ __align__(16) char VB[16384];     // 128 rows x 128B
  __shared__ __align__(16) char PB[8192];      // 4 waves x 16 rows x 128B
  const int t = threadIdx.x, l = t & 63, w = t >> 6;
  const int l15 = l & 15, lg = l >> 4;
  const int pairc = blockIdx.x >> 5;
  const int h = blockIdx.x & 31;

  const bf16* Kh = Kb + (size_t)(h >> 2) * S_LEN * HD;
  const bf16* Vh = Vt + (size_t)(h >> 2) * HD * S_LEN;
  char* Pw = PB + w * 2048;

  const int kslot = t;
  const int kj0 = kslot & 15;
  const int vj0 = kslot & 7;

#pragma unroll
  for (int phase = 0; phase < 2; phase++) {
    const int chunk = (phase == 0) ? pairc : (31 - pairc);
    const int ktiles = chunk + 1;
    const int q0 = chunk * 64 + w * 16;

    const bf16* Qh = Qb + ((size_t)h * S_LEN + q0) * HD;
    bf16x8 qf[4];
#pragma unroll
    for (int kk = 0; kk < 4; kk++)
      qf[kk] = *(const bf16x8*)(Qh + (size_t)l15 * HD + kk * 32 + lg * 8);

    // prologue: stage K(0) into KB[0]
#pragma unroll
    for (int i = 0; i < 4; i++) {
      int r = (i * 256 + kslot) >> 4;
      const bf16* src = Kh + (size_t)r * HD + (((kj0 ^ (r & 7))) << 3);
      gload_lds16(src, KB[0] + (i * 256 + w * 64) * 16);
    }

    f32x4 O[8] = {};
    float m[4], lsum[4];
#pragma unroll
    for (int r = 0; r < 4; r++) { m[r] = -1e30f; lsum[r] = 0.f; }

    for (int tt = 0; tt < ktiles; tt++) {
      const int cur = tt & 1;
      const int kv0 = tt * 64;
      const char* Kcur = KB[cur];
      const bool hasnext = (tt + 1 < ktiles);

      MEMFENCE;
      __builtin_amdgcn_s_barrier();  // B1: prev PV reads done before V overwrite
      MEMFENCE;

      // stage V(tt)
#pragma unroll
      for (int i = 0; i < 4; i++) {
        int r = (i * 256 + kslot) >> 3;
        const bf16* src = Vh + (size_t)r * S_LEN + kv0 + ((vj0 ^ (r & 7)) << 3);
        gload_lds16(src, VB + (i * 256 + w * 64) * 16);
      }
      // stage K(tt+1)
      if (hasnext) {
#pragma unroll
        for (int i = 0; i < 4; i++) {
          int r = (i * 256 + kslot) >> 4;
          const bf16* src = Kh + (size_t)(kv0 + 64 + r) * HD + ((kj0 ^ (r & 7)) << 3);
          gload_lds16(src, KB[cur ^ 1] + (i * 256 + w * 64) * 16);
        }
        asm volatile("s_waitcnt vmcnt(8)" ::: "memory");
      } else {
        asm volatile("s_waitcnt vmcnt(4)" ::: "memory");
      }
      MEMFENCE;
      __builtin_amdgcn_s_barrier();  // B1b: ALL waves' K(tt) resident
      MEMFENCE;

      // ---- QK^T from K-LDS ----
      f32x4 sc[4];
#pragma unroll
      for (int g = 0; g < 4; g++) sc[g] = (f32x4){0.f, 0.f, 0.f, 0.f};
#pragma unroll
      for (int g = 0; g < 4; g++) {
        const int r = g * 16 + l15;
        const char* Krow = Kcur + r * 256;
        const int sw = (r & 7);
#pragma unroll
        for (int kk = 0; kk < 4; kk++) {
          bf16x8 kf = *(const bf16x8*)(Krow + (((kk * 4 + lg) ^ sw) << 4));
          sc[g] = __builtin_amdgcn_mfma_f32_16x16x32_bf16(qf[kk], kf, sc[g], 0, 0, 0);
        }
      }

      // ---- online softmax ----
      const bool needmask = (kv0 + 63 > q0);
      float sv[4][4];
#pragma unroll
      for (int g = 0; g < 4; g++)
#pragma unroll
        for (int r = 0; r < 4; r++) {
          float x = sc[g][r] * SCALE_LOG2;
          if (needmask) {
            int kv = kv0 + g * 16 + l15;
            int qr = q0 + lg * 4 + r;
            if (kv > qr) x = -1e30f;
          }
          sv[g][r] = x;
        }
      float al[4];
#pragma unroll
      for (int r = 0; r < 4; r++) {
        float x = fmaxf(fmaxf(sv[0][r], sv[1][r]), fmaxf(sv[2][r], sv[3][r]));
        x = fmaxf(x, __shfl_xor(x, 1));
        x = fmaxf(x, __shfl_xor(x, 2));
        x = fmaxf(x, __shfl_xor(x, 4));
        x = fmaxf(x, __shfl_xor(x, 8));
        float mn = fmaxf(m[r], x);
        al[r] = exp2f(m[r] - mn);
        m[r] = mn;
      }
#pragma unroll
      for (int g = 0; g < 4; g++)
#pragma unroll
        for (int r = 0; r < 4; r++) sv[g][r] = exp2f(sv[g][r] - m[r]);
#pragma unroll
      for (int r = 0; r < 4; r++) {
        float x = (sv[0][r] + sv[1][r]) + (sv[2][r] + sv[3][r]);
        x += __shfl_xor(x, 1);
        x += __shfl_xor(x, 2);
        x += __shfl_xor(x, 4);
        x += __shfl_xor(x, 8);
        lsum[r] = lsum[r] * al[r] + x;
      }
#pragma unroll
      for (int dt = 0; dt < 8; dt++)
#pragma unroll
        for (int r = 0; r < 4; r++) O[dt][r] *= al[r];

      // ---- P -> per-wave LDS (swizzled), read back as A-fragments ----
#pragma unroll
      for (int g = 0; g < 4; g++)
#pragma unroll
        for (int r = 0; r < 4; r++) {
          int prow = lg * 4 + r;
          int pbyte = prow * 128 + (((g * 16 + l15) * 2) ^ ((prow & 7) << 4));
          *(bf16*)(Pw + pbyte) = (bf16)sv[g][r];
        }
      asm volatile("s_waitcnt lgkmcnt(0)" ::: "memory");
      bf16x8 pa[2];
#pragma unroll
      for (int ks = 0; ks < 2; ks++)
        pa[ks] = *(const bf16x8*)(Pw + l15 * 128 + (((ks * 4 + lg) ^ (l15 & 7)) << 4));

      // V(tt) resident for all waves before PV
      if (hasnext) asm volatile("s_waitcnt vmcnt(4)" ::: "memory");
      else         asm volatile("s_waitcnt vmcnt(0)" ::: "memory");
      MEMFENCE;
      __builtin_amdgcn_s_barrier();  // B2
      MEMFENCE;

      // ---- PV from V-LDS ----
#pragma unroll
      for (int ks = 0; ks < 2; ks++)
#pragma unroll
        for (int dt = 0; dt < 8; dt++) {
          const int r = dt * 16 + l15;
          bf16x8 vf = *(const bf16x8*)(VB + r * 128 + (((ks * 4 + lg) ^ (r & 7)) << 4));
          O[dt] = __builtin_amdgcn_mfma_f32_16x16x32_bf16(pa[ks], vf, O[dt], 0, 0, 0);
        }
    }

    // ---- epilogue ----
#pragma unroll
    for (int r = 0; r < 4; r++) {
      float inv = 1.0f / lsum[r];
      bf16* Cp = Ctx + (size_t)(q0 + lg * 4 + r) * HID_D + h * HD + l15;
#pragma unroll
      for (int dt = 0; dt < 8; dt++) Cp[dt * 16] = (bf16)(O[dt][r] * inv);
    }
  }
}

// ---------------- host launcher ------------------------------------------------
extern "C" void kernel_launch(void* const* d_in, const int* in_sizes, int n_in,
                              void* d_out, int out_size, void* d_ws, size_t ws_size,
                              hipStream_t stream) {
  const float* X  = (const float*)d_in[0];
  const float* Wq = (const float*)d_in[1];
  const float* Wk = (const float*)d_in[2];
  const float* Wv = (const float*)d_in[3];
  const float* Wo = (const float*)d_in[4];
  const float* qw = (const float*)d_in[5];
  const float* kw = (const float*)d_in[6];
  const int* pos  = (const int*)d_in[7];

  char* ws = (char*)d_ws;
  bf16* Xb    = (bf16*)ws;                         // [0,16): X bf16
  bf16* Wqkvb = (bf16*)(ws + (16ll << 20));        // [16,64): Wq|Wk|Wv (later Wo)
  bf16* Wob   = Wqkvb;
  float* QKV  = (float*)(ws + (64ll << 20));       // [64,112): QKV f32 (dead after prep)
  float* Part = (float*)(ws + (64ll << 20));       // [64,96): out-proj split-K partial
  bf16* Ctx   = (bf16*)(ws + (96ll << 20));        // [96,112): attn output bf16
  bf16* Qb    = (bf16*)(ws + (112ll << 20));       // [112,128)
  bf16* Kb    = (bf16*)(ws + (128ll << 20));       // [128,132)
  bf16* Vt    = (bf16*)(ws + (132ll << 20));       // [132,136)

  // bf16 conversions
  cvt_kernel<<<2048, 256, 0, stream>>>(X, Xb, S_LEN * HID_D / 8);
  cvt_kernel<<<2048, 256, 0, stream>>>(Wq, Wqkvb, 4096 * 4096 / 8);
  cvt_kernel<<<512, 256, 0, stream>>>(Wk, Wqkvb + 4096 * 4096, 1024 * 4096 / 8);
  cvt_kernel<<<512, 256, 0, stream>>>(Wv, Wqkvb + 5120 * 4096, 1024 * 4096 / 8);

  // fused QKV projection: [2048 x 6144] = Xb @ Wqkvb^T; 256^2 tiles, 192 blocks
  gemm256<<<dim3(24, 8, 1), 512, 0, stream>>>(Xb, Wqkvb, QKV, QKV,
                                              6144, HID_D, HID_D, 64);

  // Wo conversion (overwrites Wqkvb; stream-ordered after QKV GEMM)
  cvt_kernel<<<2048, 256, 0, stream>>>(Wo, Wob, 4096 * 4096 / 8);

  // RMSNorm + RoPE + attention layouts
  prep_kernel<<<S_LEN, 256, 0, stream>>>(QKV, qw, kw, pos, Qb, Kb, Vt);

  // flash attention
  attn_kernel<<<dim3(512), 256, 0, stream>>>(Qb, Kb, Vt, Ctx);

  // output projection, split-K=2: z=0 -> d_out, z=1 -> Part; then reduce
  gemm256<<<dim3(16, 8, 2), 512, 0, stream>>>(Ctx, Wob, (float*)d_out, Part,
                                              HID_D, HID_D, 2048, 32);
  add_kernel<<<2048, 256, 0, stream>>>((float*)d_out, Part, S_LEN * HID_D / 4);
}

// Round 7
// 379.179 us; speedup vs baseline: 1.0334x; 1.0334x over previous
//
#include <hip/hip_runtime.h>
#include <hip/hip_bf16.h>
#include <math.h>

typedef __bf16 bf16;
typedef __bf16 bf16x8 __attribute__((ext_vector_type(8)));
typedef float f32x4 __attribute__((ext_vector_type(4)));

#define S_LEN 2048
#define HID_D 4096
#define NH 32
#define NKV 8
#define HD 128
// D^-0.5 * log2(e): softmax computed in exp2 domain
#define SCALE_LOG2 (0.08838834764831843f * 1.4426950408889634f)

__device__ __forceinline__ void gload_lds16(const void* g, void* lds) {
  __builtin_amdgcn_global_load_lds((__attribute__((address_space(1))) void*)g,
                                   (__attribute__((address_space(3))) void*)lds, 16, 0, 0);
}

#define MEMFENCE asm volatile("" ::: "memory")

// ---------------- f32 -> bf16 convert (vectorized, grid-stride) ----------------
__global__ __launch_bounds__(256) void cvt_kernel(const float* __restrict__ in,
                                                  bf16* __restrict__ out, int n8) {
  int i = blockIdx.x * blockDim.x + threadIdx.x;
  int stride = gridDim.x * blockDim.x;
  for (; i < n8; i += stride) {
    const float4* p = (const float4*)in + 2 * (size_t)i;
    float4 a = p[0], b = p[1];
    bf16x8 o;
    o[0] = (bf16)a.x; o[1] = (bf16)a.y; o[2] = (bf16)a.z; o[3] = (bf16)a.w;
    o[4] = (bf16)b.x; o[5] = (bf16)b.y; o[6] = (bf16)b.z; o[7] = (bf16)b.w;
    *((bf16x8*)out + i) = o;
  }
}

// ---------------- f32 add (split-K reduce): out += part -----------------------
__global__ __launch_bounds__(256) void add_kernel(float* __restrict__ out,
                                                  const float* __restrict__ part, int n4) {
  int i = blockIdx.x * blockDim.x + threadIdx.x;
  int stride = gridDim.x * blockDim.x;
  for (; i < n4; i += stride) {
    float4 a = ((const float4*)out)[i];
    float4 b = ((const float4*)part)[i];
    a.x += b.x; a.y += b.y; a.z += b.z; a.w += b.w;
    ((float4*)out)[i] = a;
  }
}

#define LEAD_BAR                                           \
  MEMFENCE; __builtin_amdgcn_s_barrier(); MEMFENCE;        \
  asm volatile("s_waitcnt lgkmcnt(0)" ::: "memory");       \
  __builtin_amdgcn_sched_barrier(0);
#define TRAIL_BAR MEMFENCE; __builtin_amdgcn_s_barrier(); MEMFENCE;

// ---------------- 256x192 quadrant bf16 NT GEMM (full-fill QKV) ----------------
// C[M][N] = A[M][K]*B[N][K]^T. 512 thr = 8 waves (2M x 4N); wave = 128 rows x
// 48 cols. LDS 112KB: [dbuf2][A.h0 16K | A.h1 16K | B 24K]; A halves = row
// halves (wave wr reads only half wr); B monolithic 192x64k. 4 phases/tile of
// 12 MFMA: (q,ks) = (0,0),(1,0),(0,1),(1,1); B ks-frags retained in regs across
// q. Single-tile-ahead staging: all 7 gloads at p1 -> vmcnt(0) at p4 (3 phases
// of latency cover). Swizzle: chunk c at row r <-> c ^ (r&7) (128B pitch).
__global__ __launch_bounds__(512, 2) void gemm192(const bf16* __restrict__ A,
                                                  const bf16* __restrict__ B,
                                                  float* __restrict__ C,
                                                  int N, int Kfull, int T) {
  __shared__ __align__(16) char lds[114688];
  const int t = threadIdx.x, l = t & 63, w = t >> 6;
  const int wr = w >> 2, wc = w & 3;
  const int l15 = l & 15, lg = l >> 4;

  const int nwg = gridDim.x * gridDim.y;
  const int lin = blockIdx.y * gridDim.x + blockIdx.x;
  const int swz = (lin & 7) * (nwg >> 3) + (lin >> 3);
  const int n0 = (swz % gridDim.x) * 192;
  const int m0 = (swz / gridDim.x) * 256;

  auto stageAll = [&](int d, int tau) {
    const size_t kpos = (size_t)tau * 64;
#pragma unroll
    for (int hf = 0; hf < 2; hf++) {
      char* dst = lds + d * 57344 + hf * 16384;
#pragma unroll
      for (int i = 0; i < 2; i++) {
        int q = i * 512 + t;
        int r = q >> 3, c = (q & 7) ^ (r & 7);
        gload_lds16(A + (size_t)(m0 + hf * 128 + r) * Kfull + kpos + c * 8, dst + q * 16);
      }
    }
    char* dstB = lds + d * 57344 + 32768;
#pragma unroll
    for (int i = 0; i < 3; i++) {
      int q = i * 512 + t;
      int r = q >> 3, c = (q & 7) ^ (r & 7);
      gload_lds16(B + (size_t)(n0 + r) * Kfull + kpos + c * 8, dstB + q * 16);
    }
  };

  f32x4 acc[8][3] = {};
  bf16x8 a[4], b[2][3];

  auto ldsA = [&](int d, int q, int ks) {
    const char* base = lds + d * 57344 + wr * 16384;
#pragma unroll
    for (int i = 0; i < 4; i++) {
      int row = (q * 4 + i) * 16 + l15;
      a[i] = *(const bf16x8*)(base + row * 128 + (((ks * 4 + lg) ^ (row & 7)) << 4));
    }
  };
  auto ldsB = [&](int d, int ks) {
    const char* base = lds + d * 57344 + 32768;
#pragma unroll
    for (int nf = 0; nf < 3; nf++) {
      int row = wc * 48 + nf * 16 + l15;
      b[ks][nf] = *(const bf16x8*)(base + row * 128 + (((ks * 4 + lg) ^ (row & 7)) << 4));
    }
  };

#define MMA12(q, ks)                                                            \
  __builtin_amdgcn_s_setprio(1);                                                \
  _Pragma("unroll") for (int mf = 0; mf < 4; mf++)                              \
  _Pragma("unroll") for (int nf = 0; nf < 3; nf++)                              \
      acc[(q)*4 + mf][nf] = __builtin_amdgcn_mfma_f32_16x16x32_bf16(            \
          a[mf], b[ks][nf], acc[(q)*4 + mf][nf], 0, 0, 0);                      \
  __builtin_amdgcn_s_setprio(0);

  // prologue: stage tile0 only (single-ahead pipeline)
  stageAll(0, 0);
  asm volatile("s_waitcnt vmcnt(0)" ::: "memory");
  TRAIL_BAR;

  for (int tau = 0; tau < T; tau++) {
    const int d = tau & 1, dn = d ^ 1;
    const bool s1 = tau + 1 < T;
    // p1 (q0,ks0): stage next tile into dn (retired at tau-1's p4)
    if (s1) stageAll(dn, tau + 1);
    ldsA(d, 0, 0); ldsB(d, 0);
    LEAD_BAR; MMA12(0, 0); TRAIL_BAR;
    // p2 (q1,ks0): B ks0 from regs
    ldsA(d, 1, 0);
    LEAD_BAR; MMA12(1, 0); TRAIL_BAR;
    // p3 (q0,ks1)
    ldsA(d, 0, 1); ldsB(d, 1);
    LEAD_BAR; MMA12(0, 1); TRAIL_BAR;
    // p4 (q1,ks1): drain next-tile stages (had ~3 phases to land)
    ldsA(d, 1, 1);
    if (s1) { asm volatile("s_waitcnt vmcnt(0)" ::: "memory"); }
    LEAD_BAR; MMA12(1, 1); TRAIL_BAR;
  }

#pragma unroll
  for (int fi = 0; fi < 8; fi++) {
    int row = m0 + wr * 128 + fi * 16 + lg * 4;
#pragma unroll
    for (int nf = 0; nf < 3; nf++) {
      int col = n0 + wc * 48 + nf * 16 + l15;
      float* Cp = C + (size_t)row * N + col;
#pragma unroll
      for (int rr = 0; rr < 4; rr++) Cp[(size_t)rr * N] = acc[fi][nf][rr];
    }
  }
#undef MMA12
}

// ---------------- 256x256 quadrant-scheduled bf16 NT GEMM (out-proj) -----------
__global__ __launch_bounds__(512, 2) void gemm256(const bf16* __restrict__ A,
                                                  const bf16* __restrict__ B,
                                                  float* __restrict__ C0,
                                                  float* __restrict__ C1,
                                                  int N, int Kfull, int Kslice, int T) {
  __shared__ __align__(16) char lds[131072];
  const int t = threadIdx.x, l = t & 63, w = t >> 6;
  const int wr = w >> 2, wc = w & 3;
  const int l15 = l & 15, lg = l >> 4;
  const int s7 = l15 & 7;

  const int nwg = gridDim.x * gridDim.y;
  const int lin = blockIdx.y * gridDim.x + blockIdx.x;
  const int swz = (lin & 7) * (nwg >> 3) + (lin >> 3);
  const int n0 = (swz % gridDim.x) * 256;
  const int m0 = (swz / gridDim.x) * 256;
  const size_t kbase = (size_t)blockIdx.z * Kslice;
  float* __restrict__ C = blockIdx.z ? C1 : C0;

  auto stage = [&](int d, int op, int hf, int tau) {
    char* dst = lds + d * 65536 + op * 32768 + hf * 16384;
    const bf16* src = op ? B : A;
    const int rbase = (op ? n0 : m0) + hf * 128;
    const size_t kpos = kbase + (size_t)tau * 64;
#pragma unroll
    for (int i = 0; i < 2; i++) {
      int q = i * 512 + t;
      int r = q >> 3;
      int c = (q & 7) ^ (r & 7);
      gload_lds16(src + (size_t)(rbase + r) * Kfull + kpos + c * 8, dst + q * 16);
    }
  };

  f32x4 acc[2][2][4][2] = {};
  bf16x8 a[4][2], b0[2][2], b1[2][2];

  auto ldsA = [&](int d, int hf) {
    const char* base = lds + d * 65536 + hf * 16384;
#pragma unroll
    for (int mf = 0; mf < 4; mf++) {
      int row = wr * 64 + mf * 16 + l15;
#pragma unroll
      for (int ks = 0; ks < 2; ks++)
        a[mf][ks] = *(const bf16x8*)(base + row * 128 + (((ks * 4 + lg) ^ s7) << 4));
    }
  };
  auto ldsB = [&](int d, int hf, bf16x8 bb[2][2]) {
    const char* base = lds + d * 65536 + 32768 + hf * 16384;
#pragma unroll
    for (int nf = 0; nf < 2; nf++) {
      int row = wc * 32 + nf * 16 + l15;
#pragma unroll
      for (int ks = 0; ks < 2; ks++)
        bb[nf][ks] = *(const bf16x8*)(base + row * 128 + (((ks * 4 + lg) ^ s7) << 4));
    }
  };

#define MMAQ(q, r, bb)                                                          \
  __builtin_amdgcn_s_setprio(1);                                                \
  _Pragma("unroll") for (int mf = 0; mf < 4; mf++)                              \
  _Pragma("unroll") for (int nf = 0; nf < 2; nf++)                              \
  _Pragma("unroll") for (int ks = 0; ks < 2; ks++)                              \
      acc[q][r][mf][nf] = __builtin_amdgcn_mfma_f32_16x16x32_bf16(              \
          a[mf][ks], bb[nf][ks], acc[q][r][mf][nf], 0, 0, 0);                   \
  __builtin_amdgcn_s_setprio(0);

  stage(0, 0, 0, 0); stage(0, 1, 0, 0); stage(0, 1, 1, 0); stage(0, 0, 1, 0);
  stage(1, 0, 0, 1); stage(1, 1, 0, 1); stage(1, 1, 1, 1);
  asm volatile("s_waitcnt vmcnt(6)" ::: "memory");
  TRAIL_BAR;

  for (int tau = 0; tau < T; tau++) {
    const int d = tau & 1, dn = d ^ 1;
    const bool s1 = tau + 1 < T, s2 = tau + 2 < T;
    if (s1) stage(dn, 0, 1, tau + 1);
    ldsA(d, 0); ldsB(d, 0, b0);
    LEAD_BAR; MMAQ(0, 0, b0); TRAIL_BAR;
    if (s2) stage(d, 0, 0, tau + 2);
    ldsB(d, 1, b1);
    LEAD_BAR; MMAQ(0, 1, b1); TRAIL_BAR;
    if (s2) stage(d, 1, 0, tau + 2);
    ldsA(d, 1);
    LEAD_BAR; MMAQ(1, 0, b0); TRAIL_BAR;
    if (s2) stage(d, 1, 1, tau + 2);
    if (s2) { asm volatile("s_waitcnt vmcnt(6)" ::: "memory"); }
    else    { asm volatile("s_waitcnt vmcnt(0)" ::: "memory"); }
    MEMFENCE; __builtin_amdgcn_s_barrier(); MEMFENCE;
    MMAQ(1, 1, b1); TRAIL_BAR;
  }

#pragma unroll
  for (int q = 0; q < 2; q++)
#pragma unroll
    for (int r = 0; r < 2; r++)
#pragma unroll
      for (int mf = 0; mf < 4; mf++) {
        int row = m0 + q * 128 + wr * 64 + mf * 16 + lg * 4;
#pragma unroll
        for (int nf = 0; nf < 2; nf++) {
          int col = n0 + r * 128 + wc * 32 + nf * 16 + l15;
          float* Cp = C + (size_t)row * N + col;
#pragma unroll
          for (int rr = 0; rr < 4; rr++) Cp[(size_t)rr * N] = acc[q][r][mf][nf][rr];
        }
      }
#undef MMAQ
}

// ---------------- V transpose: QKV[s][5120+vc] -> Vt[vc][s] (bf16) -------------
__global__ __launch_bounds__(256) void vt_kernel(const float* __restrict__ QKV,
                                                 bf16* __restrict__ Vt) {
  __shared__ __align__(16) float tile[64][68];
  const int s0 = blockIdx.x * 64, d0 = blockIdx.y * 64;
  const int t = threadIdx.x;
#pragma unroll
  for (int i = 0; i < 4; i++) {
    int row = i * 16 + (t >> 4);
    int c4 = t & 15;
    float4 v = *(const float4*)(QKV + (size_t)(s0 + row) * 6144 + 5120 + d0 + c4 * 4);
    *(float4*)&tile[row][c4 * 4] = v;
  }
  __syncthreads();
#pragma unroll
  for (int i = 0; i < 2; i++) {
    int slot = i * 256 + t;
    int dr = slot >> 3, ch = slot & 7;
    bf16x8 o;
#pragma unroll
    for (int j = 0; j < 8; j++) o[j] = (bf16)tile[ch * 8 + j][dr];
    *(bf16x8*)(Vt + (size_t)(d0 + dr) * S_LEN + s0 + ch * 8) = o;
  }
}

// ---------------- fused RMSNorm + RoPE + layout kernel (Q,K only) --------------
__global__ __launch_bounds__(256) void prep_kernel(const float* __restrict__ QKV,
                                                   const float* __restrict__ qw,
                                                   const float* __restrict__ kw,
                                                   const int* __restrict__ pos_ids,
                                                   bf16* __restrict__ Qb,
                                                   bf16* __restrict__ Kb) {
  __shared__ __align__(16) float row[5120];
  __shared__ float cs[64];
  __shared__ float red[8];
  const int s = blockIdx.x, t = threadIdx.x;

  const float4* src = (const float4*)(QKV + (size_t)s * 6144);
#pragma unroll
  for (int i = 0; i < 5; i++) ((float4*)row)[t + i * 256] = src[t + i * 256];

  if (t < 32) {
    float p = (float)pos_ids[s];
    float ang = p * powf(10000.0f, -(float)t * (1.0f / 32.0f));
    float sn, cn;
    sincosf(ang, &sn, &cn);
    cs[t] = cn;
    cs[32 + t] = sn;
  }
  __syncthreads();

  float aq = 0.f, ak = 0.f;
  for (int i = t; i < 4096; i += 256) { float v = row[i]; aq += v * v; }
  for (int i = 4096 + t; i < 5120; i += 256) { float v = row[i]; ak += v * v; }
#pragma unroll
  for (int off = 32; off; off >>= 1) {
    aq += __shfl_down(aq, off);
    ak += __shfl_down(ak, off);
  }
  if ((t & 63) == 0) { red[t >> 6] = aq; red[4 + (t >> 6)] = ak; }
  __syncthreads();
  const float scq = rsqrtf((red[0] + red[1] + red[2] + red[3]) * (1.0f / 4096.0f) + 1e-6f);
  const float sck = rsqrtf((red[4] + red[5] + red[6] + red[7]) * (1.0f / 1024.0f) + 1e-6f);

  for (int e = t; e < 4096; e += 256) {
    int d = e & 127;
    int hh = e >> 7;
    float val = row[e] * scq * qw[e];
    float o;
    if (d < 32)       o = val * cs[d] - (row[e + 32] * scq * qw[e + 32]) * cs[32 + d];
    else if (d < 64)  o = val * cs[d - 32] + (row[e - 32] * scq * qw[e - 32]) * cs[d];
    else              o = val;
    Qb[((size_t)hh * S_LEN + s) * HD + d] = (bf16)o;
  }
  for (int e = t; e < 1024; e += 256) {
    int d = e & 127;
    int hh = e >> 7;
    int ri = 4096 + e;
    float val = row[ri] * sck * kw[e];
    float o;
    if (d < 32)       o = val * cs[d] - (row[ri + 32] * sck * kw[e + 32]) * cs[32 + d];
    else if (d < 64)  o = val * cs[d - 32] + (row[ri - 32] * sck * kw[e - 32]) * cs[d];
    else              o = val;
    Kb[((size_t)hh * S_LEN + s) * HD + d] = (bf16)o;
  }
}

// ---------------- flash attention (GQA, causal, single-barrier pipeline) -------
// grid = 512: blockIdx.x = pair*32 + head; chunks (c, 31-c) of 64 q rows ->
// uniform 33 kv-tiles/block. K AND V double-buffered (72KB, 2 blocks/CU).
// Per tile: ONE barrier. Stages for t+1 issued right after QK(t) (hide under
// softmax+PV); vmcnt(0) at loop top just before the barrier.
__global__ __launch_bounds__(256, 2) void attn_kernel(const bf16* __restrict__ Qb,
                                                      const bf16* __restrict__ Kb,
                                                      const bf16* __restrict__ Vt,
                                                      bf16* __restrict__ Ctx) {
  __shared__ __align__(16) char KB[2][16384];  // 64 rows x 256B each
  __shared__ __align__(16) char VB[2][16384];  // 128 d-rows x 128B each
  __shared__ __align__(16) char PB[8192];      // 4 waves x 16 rows x 128B
  const int t = threadIdx.x, l = t & 63, w = t >> 6;
  const int l15 = l & 15, lg = l >> 4;
  const int pairc = blockIdx.x >> 5;
  const int h = blockIdx.x & 31;

  const bf16* Kh = Kb + (size_t)(h >> 2) * S_LEN * HD;
  const bf16* Vh = Vt + (size_t)(h >> 2) * HD * S_LEN;
  char* Pw = PB + w * 2048;

  const int kj0 = t & 15;
  const int vj0 = t & 7;

  auto stageK = [&](int buf, int kvbase) {
#pragma unroll
    for (int i = 0; i < 4; i++) {
      int r = (i * 256 + t) >> 4;
      const bf16* src = Kh + (size_t)(kvbase + r) * HD + ((kj0 ^ (r & 7)) << 3);
      gload_lds16(src, KB[buf] + (i * 256 + w * 64) * 16);
    }
  };
  auto stageV = [&](int buf, int kvbase) {
#pragma unroll
    for (int i = 0; i < 4; i++) {
      int r = (i * 256 + t) >> 3;
      const bf16* src = Vh + (size_t)r * S_LEN + kvbase + ((vj0 ^ (r & 7)) << 3);
      gload_lds16(src, VB[buf] + (i * 256 + w * 64) * 16);
    }
  };

#pragma unroll
  for (int phase = 0; phase < 2; phase++) {
    const int chunk = (phase == 0) ? pairc : (31 - pairc);
    const int ktiles = chunk + 1;
    const int q0 = chunk * 64 + w * 16;

    const bf16* Qh = Qb + ((size_t)h * S_LEN + q0) * HD;
    bf16x8 qf[4];
#pragma unroll
    for (int kk = 0; kk < 4; kk++)
      qf[kk] = *(const bf16x8*)(Qh + (size_t)l15 * HD + kk * 32 + lg * 8);

    // prologue: stage tile 0
    stageK(0, 0);
    stageV(0, 0);

    f32x4 O[8] = {};
    float m[4], lsum[4];
#pragma unroll
    for (int r = 0; r < 4; r++) { m[r] = -1e30f; lsum[r] = 0.f; }

    for (int tt = 0; tt < ktiles; tt++) {
      const int cur = tt & 1;
      const int kv0 = tt * 64;
      const char* Kcur = KB[cur];
      const bool hasnext = (tt + 1 < ktiles);

      // all stages for this tile (issued last iter / prologue) must be resident
      asm volatile("s_waitcnt vmcnt(0)" ::: "memory");
      MEMFENCE;
      __builtin_amdgcn_s_barrier();
      MEMFENCE;

      // ---- QK^T from K-LDS ----
      f32x4 sc[4];
#pragma unroll
      for (int g = 0; g < 4; g++) sc[g] = (f32x4){0.f, 0.f, 0.f, 0.f};
#pragma unroll
      for (int g = 0; g < 4; g++) {
        const int r = g * 16 + l15;
        const char* Krow = Kcur + r * 256;
        const int sw = (r & 7);
#pragma unroll
        for (int kk = 0; kk < 4; kk++) {
          bf16x8 kf = *(const bf16x8*)(Krow + (((kk * 4 + lg) ^ sw) << 4));
          sc[g] = __builtin_amdgcn_mfma_f32_16x16x32_bf16(qf[kk], kf, sc[g], 0, 0, 0);
        }
      }

      // ---- issue next-tile stages: latency hides under softmax + PV ----
      if (hasnext) {
        stageK(cur ^ 1, kv0 + 64);
        stageV(cur ^ 1, kv0 + 64);
      }

      // ---- online softmax ----
      const bool needmask = (kv0 + 63 > q0);
      float sv[4][4];
#pragma unroll
      for (int g = 0; g < 4; g++)
#pragma unroll
        for (int r = 0; r < 4; r++) {
          float x = sc[g][r] * SCALE_LOG2;
          if (needmask) {
            int kv = kv0 + g * 16 + l15;
            int qr = q0 + lg * 4 + r;
            if (kv > qr) x = -1e30f;
          }
          sv[g][r] = x;
        }
      float al[4];
#pragma unroll
      for (int r = 0; r < 4; r++) {
        float x = fmaxf(fmaxf(sv[0][r], sv[1][r]), fmaxf(sv[2][r], sv[3][r]));
        x = fmaxf(x, __shfl_xor(x, 1));
        x = fmaxf(x, __shfl_xor(x, 2));
        x = fmaxf(x, __shfl_xor(x, 4));
        x = fmaxf(x, __shfl_xor(x, 8));
        float mn = fmaxf(m[r], x);
        al[r] = exp2f(m[r] - mn);
        m[r] = mn;
      }
#pragma unroll
      for (int g = 0; g < 4; g++)
#pragma unroll
        for (int r = 0; r < 4; r++) sv[g][r] = exp2f(sv[g][r] - m[r]);
#pragma unroll
      for (int r = 0; r < 4; r++) {
        float x = (sv[0][r] + sv[1][r]) + (sv[2][r] + sv[3][r]);
        x += __shfl_xor(x, 1);
        x += __shfl_xor(x, 2);
        x += __shfl_xor(x, 4);
        x += __shfl_xor(x, 8);
        lsum[r] = lsum[r] * al[r] + x;
      }
#pragma unroll
      for (int dt = 0; dt < 8; dt++)
#pragma unroll
        for (int r = 0; r < 4; r++) O[dt][r] *= al[r];

      // ---- P -> per-wave LDS (swizzled), read back as A-fragments ----
#pragma unroll
      for (int g = 0; g < 4; g++)
#pragma unroll
        for (int r = 0; r < 4; r++) {
          int prow = lg * 4 + r;
          int pbyte = prow * 128 + (((g * 16 + l15) * 2) ^ ((prow & 7) << 4));
          *(bf16*)(Pw + pbyte) = (bf16)sv[g][r];
        }
      asm volatile("s_waitcnt lgkmcnt(0)" ::: "memory");
      bf16x8 pa[2];
#pragma unroll
      for (int ks = 0; ks < 2; ks++)
        pa[ks] = *(const bf16x8*)(Pw + l15 * 128 + (((ks * 4 + lg) ^ (l15 & 7)) << 4));

      // ---- PV from V-LDS ----
#pragma unroll
      for (int ks = 0; ks < 2; ks++)
#pragma unroll
        for (int dt = 0; dt < 8; dt++) {
          const int r = dt * 16 + l15;
          bf16x8 vf = *(const bf16x8*)(VB[cur] + r * 128 + (((ks * 4 + lg) ^ (r & 7)) << 4));
          O[dt] = __builtin_amdgcn_mfma_f32_16x16x32_bf16(pa[ks], vf, O[dt], 0, 0, 0);
        }
    }

    // all waves must finish last tile before next phase's prologue staging
    MEMFENCE;
    __builtin_amdgcn_s_barrier();
    MEMFENCE;

    // ---- epilogue ----
#pragma unroll
    for (int r = 0; r < 4; r++) {
      float inv = 1.0f / lsum[r];
      bf16* Cp = Ctx + (size_t)(q0 + lg * 4 + r) * HID_D + h * HD + l15;
#pragma unroll
      for (int dt = 0; dt < 8; dt++) Cp[dt * 16] = (bf16)(O[dt][r] * inv);
    }
  }
}

// ---------------- host launcher ------------------------------------------------
extern "C" void kernel_launch(void* const* d_in, const int* in_sizes, int n_in,
                              void* d_out, int out_size, void* d_ws, size_t ws_size,
                              hipStream_t stream) {
  const float* X  = (const float*)d_in[0];
  const float* Wq = (const float*)d_in[1];
  const float* Wk = (const float*)d_in[2];
  const float* Wv = (const float*)d_in[3];
  const float* Wo = (const float*)d_in[4];
  const float* qw = (const float*)d_in[5];
  const float* kw = (const float*)d_in[6];
  const int* pos  = (const int*)d_in[7];

  char* ws = (char*)d_ws;
  bf16* Xb    = (bf16*)ws;                         // [0,16): X bf16
  bf16* Wqkvb = (bf16*)(ws + (16ll << 20));        // [16,64): Wq|Wk|Wv (later Wo)
  bf16* Wob   = Wqkvb;
  float* QKV  = (float*)(ws + (64ll << 20));       // [64,112): QKV f32 (dead after prep/vt)
  float* Part = (float*)(ws + (64ll << 20));       // [64,96): out-proj split-K partial
  bf16* Ctx   = (bf16*)(ws + (96ll << 20));        // [96,112): attn output bf16
  bf16* Qb    = (bf16*)(ws + (112ll << 20));       // [112,128)
  bf16* Kb    = (bf16*)(ws + (128ll << 20));       // [128,132)
  bf16* Vt    = (bf16*)(ws + (132ll << 20));       // [132,136)

  // bf16 conversions
  cvt_kernel<<<2048, 256, 0, stream>>>(X, Xb, S_LEN * HID_D / 8);
  cvt_kernel<<<2048, 256, 0, stream>>>(Wq, Wqkvb, 4096 * 4096 / 8);
  cvt_kernel<<<512, 256, 0, stream>>>(Wk, Wqkvb + 4096 * 4096, 1024 * 4096 / 8);
  cvt_kernel<<<512, 256, 0, stream>>>(Wv, Wqkvb + 5120 * 4096, 1024 * 4096 / 8);

  // fused QKV projection: [2048 x 6144] = Xb @ Wqkvb^T; 256x192 tiles, 256 blocks
  gemm192<<<dim3(32, 8, 1), 512, 0, stream>>>(Xb, Wqkvb, QKV, 6144, HID_D, 64);

  // Wo conversion (overwrites Wqkvb; stream-ordered after QKV GEMM)
  cvt_kernel<<<2048, 256, 0, stream>>>(Wo, Wob, 4096 * 4096 / 8);

  // V transpose + RMSNorm/RoPE layouts
  vt_kernel<<<dim3(32, 16), 256, 0, stream>>>(QKV, Vt);
  prep_kernel<<<S_LEN, 256, 0, stream>>>(QKV, qw, kw, pos, Qb, Kb);

  // flash attention
  attn_kernel<<<dim3(512), 256, 0, stream>>>(Qb, Kb, Vt, Ctx);

  // output projection, split-K=2: z=0 -> d_out, z=1 -> Part; then reduce
  gemm256<<<dim3(16, 8, 2), 512, 0, stream>>>(Ctx, Wob, (float*)d_out, Part,
                                              HID_D, HID_D, 2048, 32);
  add_kernel<<<2048, 256, 0, stream>>>((float*)d_out, Part, S_LEN * HID_D / 4);
}

// Round 8
// 354.284 us; speedup vs baseline: 1.1060x; 1.0703x over previous
//
#include <hip/hip_runtime.h>
#include <hip/hip_bf16.h>
#include <math.h>

typedef __bf16 bf16;
typedef __bf16 bf16x8 __attribute__((ext_vector_type(8)));
typedef float f32x4 __attribute__((ext_vector_type(4)));

#define S_LEN 2048
#define HID_D 4096
#define NH 32
#define NKV 8
#define HD 128
// D^-0.5 * log2(e): softmax computed in exp2 domain
#define SCALE_LOG2 (0.08838834764831843f * 1.4426950408889634f)

__device__ __forceinline__ void gload_lds16(const void* g, void* lds) {
  __builtin_amdgcn_global_load_lds((__attribute__((address_space(1))) void*)g,
                                   (__attribute__((address_space(3))) void*)lds, 16, 0, 0);
}

#define MEMFENCE asm volatile("" ::: "memory")

// ---------------- f32 -> bf16 convert (vectorized, grid-stride) ----------------
__global__ __launch_bounds__(256) void cvt_kernel(const float* __restrict__ in,
                                                  bf16* __restrict__ out, int n8) {
  int i = blockIdx.x * blockDim.x + threadIdx.x;
  int stride = gridDim.x * blockDim.x;
  for (; i < n8; i += stride) {
    const float4* p = (const float4*)in + 2 * (size_t)i;
    float4 a = p[0], b = p[1];
    bf16x8 o;
    o[0] = (bf16)a.x; o[1] = (bf16)a.y; o[2] = (bf16)a.z; o[3] = (bf16)a.w;
    o[4] = (bf16)b.x; o[5] = (bf16)b.y; o[6] = (bf16)b.z; o[7] = (bf16)b.w;
    *((bf16x8*)out + i) = o;
  }
}

// ---------------- single-barrier-per-tile bf16 NT GEMM -------------------------
// C[M][N] = A[M][K]*B[N][K]^T. 512 thr = 8 waves (2M x 4N); wave tile
// (BM/2) x (BN/4). LDS = 2 dbuf x [(BM+BN) rows x 128B] (one BK=64 tile,
// A then B). Per K-tile: issue stage gloads for t+1 into retired buffer,
// then PLAIN ds loads + all MFMAs (compiler emits counted lgkm waits and
// interleaves ds under MFMA), then ONE vmcnt(0)+barrier. WAR-safe: buffer
// d^1 was last read in tile t-1, and each wave's ds reads complete before
// its last MFMA issue, which precedes barrier arrival.
// Swizzle: 16B chunk c of row r stored/read at slot c ^ (r&7) (0 conflicts).
template <int BM, int BN>
__global__ __launch_bounds__(512, 2) void gemm_s(const bf16* __restrict__ A,
                                                 const bf16* __restrict__ B,
                                                 float* __restrict__ C,
                                                 int N, int Kfull, int T) {
  constexpr int MFr = BM / 32;        // A frags per wave (wave rows = BM/2)
  constexpr int NFr = BN / 64;        // B frags per wave (wave cols = BN/4)
  constexpr int NL = (BM + BN) / 64;  // gload insts per tile (8KB each)
  constexpr int TILE = (BM + BN) * 128;

  __shared__ __align__(16) char lds[2 * TILE];
  const int t = threadIdx.x, l = t & 63, w = t >> 6;
  const int wr = w >> 2, wc = w & 3;
  const int l15 = l & 15, lg = l >> 4;

  // XCD-aware block swizzle (nwg divisible by 8 for all launches)
  const int nwg = gridDim.x * gridDim.y;
  const int lin = blockIdx.y * gridDim.x + blockIdx.x;
  const int swz = (lin & 7) * (nwg >> 3) + (lin >> 3);
  const int n0 = (swz % gridDim.x) * BN;
  const int m0 = (swz / gridDim.x) * BM;

  auto stage = [&](int d, int tau) {
    char* dst = lds + d * TILE;
    const size_t kpos = (size_t)tau * 64;
#pragma unroll
    for (int i = 0; i < NL; i++) {
      int q = i * 512 + t;
      int r = q >> 3;                 // row in [A | B] concatenation
      int c = (q & 7) ^ (r & 7);      // inverse-swizzled source chunk
      const bf16* src = (i * 512 < BM * 8)
                            ? (A + (size_t)(m0 + r) * Kfull)
                            : (B + (size_t)(n0 + (r - BM)) * Kfull);
      gload_lds16(src + kpos + c * 8, dst + q * 16);
    }
  };

  f32x4 acc[MFr][NFr] = {};

  // prologue
  stage(0, 0);
  asm volatile("s_waitcnt vmcnt(0)" ::: "memory");
  MEMFENCE; __builtin_amdgcn_s_barrier(); MEMFENCE;

  for (int tau = 0; tau < T; tau++) {
    const int d = tau & 1;
    if (tau + 1 < T) stage(d ^ 1, tau + 1);

    const char* Ab = lds + d * TILE;
    const char* Bb = Ab + BM * 128;
    bf16x8 a[MFr][2], b[NFr][2];
#pragma unroll
    for (int mf = 0; mf < MFr; mf++) {
      const int row = wr * (BM / 2) + mf * 16 + l15;
#pragma unroll
      for (int ks = 0; ks < 2; ks++)
        a[mf][ks] = *(const bf16x8*)(Ab + row * 128 + (((ks * 4 + lg) ^ (row & 7)) << 4));
    }
#pragma unroll
    for (int nf = 0; nf < NFr; nf++) {
      const int row = wc * (BN / 4) + nf * 16 + l15;
#pragma unroll
      for (int ks = 0; ks < 2; ks++)
        b[nf][ks] = *(const bf16x8*)(Bb + row * 128 + (((ks * 4 + lg) ^ (row & 7)) << 4));
    }
#pragma unroll
    for (int mf = 0; mf < MFr; mf++)
#pragma unroll
      for (int nf = 0; nf < NFr; nf++)
#pragma unroll
        for (int ks = 0; ks < 2; ks++)
          acc[mf][nf] = __builtin_amdgcn_mfma_f32_16x16x32_bf16(a[mf][ks], b[nf][ks],
                                                               acc[mf][nf], 0, 0, 0);

    asm volatile("s_waitcnt vmcnt(0)" ::: "memory");
    MEMFENCE; __builtin_amdgcn_s_barrier(); MEMFENCE;
  }

  // epilogue
#pragma unroll
  for (int mf = 0; mf < MFr; mf++) {
    int row = m0 + wr * (BM / 2) + mf * 16 + lg * 4;
#pragma unroll
    for (int nf = 0; nf < NFr; nf++) {
      int col = n0 + wc * (BN / 4) + nf * 16 + l15;
      float* Cp = C + (size_t)row * N + col;
#pragma unroll
      for (int rr = 0; rr < 4; rr++) Cp[(size_t)rr * N] = acc[mf][nf][rr];
    }
  }
}

// ---------------- V transpose: QKV[s][5120+vc] -> Vt[vc][s] (bf16) -------------
__global__ __launch_bounds__(256) void vt_kernel(const float* __restrict__ QKV,
                                                 bf16* __restrict__ Vt) {
  __shared__ __align__(16) float tile[64][68];
  const int s0 = blockIdx.x * 64, d0 = blockIdx.y * 64;
  const int t = threadIdx.x;
#pragma unroll
  for (int i = 0; i < 4; i++) {
    int row = i * 16 + (t >> 4);
    int c4 = t & 15;
    float4 v = *(const float4*)(QKV + (size_t)(s0 + row) * 6144 + 5120 + d0 + c4 * 4);
    *(float4*)&tile[row][c4 * 4] = v;
  }
  __syncthreads();
#pragma unroll
  for (int i = 0; i < 2; i++) {
    int slot = i * 256 + t;
    int dr = slot >> 3, ch = slot & 7;
    bf16x8 o;
#pragma unroll
    for (int j = 0; j < 8; j++) o[j] = (bf16)tile[ch * 8 + j][dr];
    *(bf16x8*)(Vt + (size_t)(d0 + dr) * S_LEN + s0 + ch * 8) = o;
  }
}

// ---------------- fused RMSNorm + RoPE + layout kernel (Q,K only) --------------
__global__ __launch_bounds__(256) void prep_kernel(const float* __restrict__ QKV,
                                                   const float* __restrict__ qw,
                                                   const float* __restrict__ kw,
                                                   const int* __restrict__ pos_ids,
                                                   bf16* __restrict__ Qb,
                                                   bf16* __restrict__ Kb) {
  __shared__ __align__(16) float row[5120];
  __shared__ float cs[64];
  __shared__ float red[8];
  const int s = blockIdx.x, t = threadIdx.x;

  const float4* src = (const float4*)(QKV + (size_t)s * 6144);
#pragma unroll
  for (int i = 0; i < 5; i++) ((float4*)row)[t + i * 256] = src[t + i * 256];

  if (t < 32) {
    float p = (float)pos_ids[s];
    float ang = p * powf(10000.0f, -(float)t * (1.0f / 32.0f));
    float sn, cn;
    sincosf(ang, &sn, &cn);
    cs[t] = cn;
    cs[32 + t] = sn;
  }
  __syncthreads();

  float aq = 0.f, ak = 0.f;
  for (int i = t; i < 4096; i += 256) { float v = row[i]; aq += v * v; }
  for (int i = 4096 + t; i < 5120; i += 256) { float v = row[i]; ak += v * v; }
#pragma unroll
  for (int off = 32; off; off >>= 1) {
    aq += __shfl_down(aq, off);
    ak += __shfl_down(ak, off);
  }
  if ((t & 63) == 0) { red[t >> 6] = aq; red[4 + (t >> 6)] = ak; }
  __syncthreads();
  const float scq = rsqrtf((red[0] + red[1] + red[2] + red[3]) * (1.0f / 4096.0f) + 1e-6f);
  const float sck = rsqrtf((red[4] + red[5] + red[6] + red[7]) * (1.0f / 1024.0f) + 1e-6f);

  for (int e = t; e < 4096; e += 256) {
    int d = e & 127;
    int hh = e >> 7;
    float val = row[e] * scq * qw[e];
    float o;
    if (d < 32)       o = val * cs[d] - (row[e + 32] * scq * qw[e + 32]) * cs[32 + d];
    else if (d < 64)  o = val * cs[d - 32] + (row[e - 32] * scq * qw[e - 32]) * cs[d];
    else              o = val;
    Qb[((size_t)hh * S_LEN + s) * HD + d] = (bf16)o;
  }
  for (int e = t; e < 1024; e += 256) {
    int d = e & 127;
    int hh = e >> 7;
    int ri = 4096 + e;
    float val = row[ri] * sck * kw[e];
    float o;
    if (d < 32)       o = val * cs[d] - (row[ri + 32] * sck * kw[e + 32]) * cs[32 + d];
    else if (d < 64)  o = val * cs[d - 32] + (row[ri - 32] * sck * kw[e - 32]) * cs[d];
    else              o = val;
    Kb[((size_t)hh * S_LEN + s) * HD + d] = (bf16)o;
  }
}

// ---------------- flash attention (GQA, causal, single-barrier pipeline) -------
__global__ __launch_bounds__(256, 2) void attn_kernel(const bf16* __restrict__ Qb,
                                                      const bf16* __restrict__ Kb,
                                                      const bf16* __restrict__ Vt,
                                                      bf16* __restrict__ Ctx) {
  __shared__ __align__(16) char KB[2][16384];  // 64 rows x 256B each
  __shared__ __align__(16) char VB[2][16384];  // 128 d-rows x 128B each
  __shared__ __align__(16) char PB[8192];      // 4 waves x 16 rows x 128B
  const int t = threadIdx.x, l = t & 63, w = t >> 6;
  const int l15 = l & 15, lg = l >> 4;
  const int pairc = blockIdx.x >> 5;
  const int h = blockIdx.x & 31;

  const bf16* Kh = Kb + (size_t)(h >> 2) * S_LEN * HD;
  const bf16* Vh = Vt + (size_t)(h >> 2) * HD * S_LEN;
  char* Pw = PB + w * 2048;

  const int kj0 = t & 15;
  const int vj0 = t & 7;

  auto stageK = [&](int buf, int kvbase) {
#pragma unroll
    for (int i = 0; i < 4; i++) {
      int r = (i * 256 + t) >> 4;
      const bf16* src = Kh + (size_t)(kvbase + r) * HD + ((kj0 ^ (r & 7)) << 3);
      gload_lds16(src, KB[buf] + (i * 256 + w * 64) * 16);
    }
  };
  auto stageV = [&](int buf, int kvbase) {
#pragma unroll
    for (int i = 0; i < 4; i++) {
      int r = (i * 256 + t) >> 3;
      const bf16* src = Vh + (size_t)r * S_LEN + kvbase + ((vj0 ^ (r & 7)) << 3);
      gload_lds16(src, VB[buf] + (i * 256 + w * 64) * 16);
    }
  };

#pragma unroll
  for (int phase = 0; phase < 2; phase++) {
    const int chunk = (phase == 0) ? pairc : (31 - pairc);
    const int ktiles = chunk + 1;
    const int q0 = chunk * 64 + w * 16;

    const bf16* Qh = Qb + ((size_t)h * S_LEN + q0) * HD;
    bf16x8 qf[4];
#pragma unroll
    for (int kk = 0; kk < 4; kk++)
      qf[kk] = *(const bf16x8*)(Qh + (size_t)l15 * HD + kk * 32 + lg * 8);

    // prologue: stage tile 0
    stageK(0, 0);
    stageV(0, 0);

    f32x4 O[8] = {};
    float m[4], lsum[4];
#pragma unroll
    for (int r = 0; r < 4; r++) { m[r] = -1e30f; lsum[r] = 0.f; }

    for (int tt = 0; tt < ktiles; tt++) {
      const int cur = tt & 1;
      const int kv0 = tt * 64;
      const char* Kcur = KB[cur];
      const bool hasnext = (tt + 1 < ktiles);

      // all stages for this tile (issued last iter / prologue) must be resident
      asm volatile("s_waitcnt vmcnt(0)" ::: "memory");
      MEMFENCE;
      __builtin_amdgcn_s_barrier();
      MEMFENCE;

      // ---- QK^T from K-LDS ----
      f32x4 sc[4];
#pragma unroll
      for (int g = 0; g < 4; g++) sc[g] = (f32x4){0.f, 0.f, 0.f, 0.f};
#pragma unroll
      for (int g = 0; g < 4; g++) {
        const int r = g * 16 + l15;
        const char* Krow = Kcur + r * 256;
        const int sw = (r & 7);
#pragma unroll
        for (int kk = 0; kk < 4; kk++) {
          bf16x8 kf = *(const bf16x8*)(Krow + (((kk * 4 + lg) ^ sw) << 4));
          sc[g] = __builtin_amdgcn_mfma_f32_16x16x32_bf16(qf[kk], kf, sc[g], 0, 0, 0);
        }
      }

      // ---- issue next-tile stages: latency hides under softmax + PV ----
      if (hasnext) {
        stageK(cur ^ 1, kv0 + 64);
        stageV(cur ^ 1, kv0 + 64);
      }

      // ---- online softmax ----
      const bool needmask = (kv0 + 63 > q0);
      float sv[4][4];
#pragma unroll
      for (int g = 0; g < 4; g++)
#pragma unroll
        for (int r = 0; r < 4; r++) {
          float x = sc[g][r] * SCALE_LOG2;
          if (needmask) {
            int kv = kv0 + g * 16 + l15;
            int qr = q0 + lg * 4 + r;
            if (kv > qr) x = -1e30f;
          }
          sv[g][r] = x;
        }
      float al[4];
#pragma unroll
      for (int r = 0; r < 4; r++) {
        float x = fmaxf(fmaxf(sv[0][r], sv[1][r]), fmaxf(sv[2][r], sv[3][r]));
        x = fmaxf(x, __shfl_xor(x, 1));
        x = fmaxf(x, __shfl_xor(x, 2));
        x = fmaxf(x, __shfl_xor(x, 4));
        x = fmaxf(x, __shfl_xor(x, 8));
        float mn = fmaxf(m[r], x);
        al[r] = exp2f(m[r] - mn);
        m[r] = mn;
      }
#pragma unroll
      for (int g = 0; g < 4; g++)
#pragma unroll
        for (int r = 0; r < 4; r++) sv[g][r] = exp2f(sv[g][r] - m[r]);
#pragma unroll
      for (int r = 0; r < 4; r++) {
        float x = (sv[0][r] + sv[1][r]) + (sv[2][r] + sv[3][r]);
        x += __shfl_xor(x, 1);
        x += __shfl_xor(x, 2);
        x += __shfl_xor(x, 4);
        x += __shfl_xor(x, 8);
        lsum[r] = lsum[r] * al[r] + x;
      }
#pragma unroll
      for (int dt = 0; dt < 8; dt++)
#pragma unroll
        for (int r = 0; r < 4; r++) O[dt][r] *= al[r];

      // ---- P -> per-wave LDS (swizzled), read back as A-fragments ----
#pragma unroll
      for (int g = 0; g < 4; g++)
#pragma unroll
        for (int r = 0; r < 4; r++) {
          int prow = lg * 4 + r;
          int pbyte = prow * 128 + (((g * 16 + l15) * 2) ^ ((prow & 7) << 4));
          *(bf16*)(Pw + pbyte) = (bf16)sv[g][r];
        }
      asm volatile("s_waitcnt lgkmcnt(0)" ::: "memory");
      bf16x8 pa[2];
#pragma unroll
      for (int ks = 0; ks < 2; ks++)
        pa[ks] = *(const bf16x8*)(Pw + l15 * 128 + (((ks * 4 + lg) ^ (l15 & 7)) << 4));

      // ---- PV from V-LDS ----
#pragma unroll
      for (int ks = 0; ks < 2; ks++)
#pragma unroll
        for (int dt = 0; dt < 8; dt++) {
          const int r = dt * 16 + l15;
          bf16x8 vf = *(const bf16x8*)(VB[cur] + r * 128 + (((ks * 4 + lg) ^ (r & 7)) << 4));
          O[dt] = __builtin_amdgcn_mfma_f32_16x16x32_bf16(pa[ks], vf, O[dt], 0, 0, 0);
        }
    }

    // all waves must finish last tile before next phase's prologue staging
    MEMFENCE;
    __builtin_amdgcn_s_barrier();
    MEMFENCE;

    // ---- epilogue ----
#pragma unroll
    for (int r = 0; r < 4; r++) {
      float inv = 1.0f / lsum[r];
      bf16* Cp = Ctx + (size_t)(q0 + lg * 4 + r) * HID_D + h * HD + l15;
#pragma unroll
      for (int dt = 0; dt < 8; dt++) Cp[dt * 16] = (bf16)(O[dt][r] * inv);
    }
  }
}

// ---------------- host launcher ------------------------------------------------
extern "C" void kernel_launch(void* const* d_in, const int* in_sizes, int n_in,
                              void* d_out, int out_size, void* d_ws, size_t ws_size,
                              hipStream_t stream) {
  const float* X  = (const float*)d_in[0];
  const float* Wq = (const float*)d_in[1];
  const float* Wk = (const float*)d_in[2];
  const float* Wv = (const float*)d_in[3];
  const float* Wo = (const float*)d_in[4];
  const float* qw = (const float*)d_in[5];
  const float* kw = (const float*)d_in[6];
  const int* pos  = (const int*)d_in[7];

  char* ws = (char*)d_ws;
  bf16* Xb    = (bf16*)ws;                         // [0,16): X bf16
  bf16* Wqkvb = (bf16*)(ws + (16ll << 20));        // [16,64): Wq|Wk|Wv (later Wo)
  bf16* Wob   = Wqkvb;
  float* QKV  = (float*)(ws + (64ll << 20));       // [64,112): QKV f32 (dead after prep/vt)
  bf16* Ctx   = (bf16*)(ws + (96ll << 20));        // [96,112): attn output bf16
  bf16* Qb    = (bf16*)(ws + (112ll << 20));       // [112,128)
  bf16* Kb    = (bf16*)(ws + (128ll << 20));       // [128,132)
  bf16* Vt    = (bf16*)(ws + (132ll << 20));       // [132,136)

  // bf16 conversions
  cvt_kernel<<<2048, 256, 0, stream>>>(X, Xb, S_LEN * HID_D / 8);
  cvt_kernel<<<2048, 256, 0, stream>>>(Wq, Wqkvb, 4096 * 4096 / 8);
  cvt_kernel<<<512, 256, 0, stream>>>(Wk, Wqkvb + 4096 * 4096, 1024 * 4096 / 8);
  cvt_kernel<<<512, 256, 0, stream>>>(Wv, Wqkvb + 5120 * 4096, 1024 * 4096 / 8);

  // fused QKV projection: [2048 x 6144] = Xb @ Wqkvb^T; 128x384 tiles, 256 blocks
  gemm_s<128, 384><<<dim3(16, 16), 512, 0, stream>>>(Xb, Wqkvb, QKV, 6144, HID_D, 64);

  // Wo conversion (overwrites Wqkvb; stream-ordered after QKV GEMM)
  cvt_kernel<<<2048, 256, 0, stream>>>(Wo, Wob, 4096 * 4096 / 8);

  // V transpose + RMSNorm/RoPE layouts
  vt_kernel<<<dim3(32, 16), 256, 0, stream>>>(QKV, Vt);
  prep_kernel<<<S_LEN, 256, 0, stream>>>(QKV, qw, kw, pos, Qb, Kb);

  // flash attention
  attn_kernel<<<dim3(512), 256, 0, stream>>>(Qb, Kb, Vt, Ctx);

  // output projection: [2048 x 4096] = Ctx @ Wob^T; 128x256 tiles, 256 blocks
  gemm_s<128, 256><<<dim3(16, 16), 512, 0, stream>>>(Ctx, Wob, (float*)d_out,
                                                     HID_D, HID_D, 64);
}